// Round 6
// baseline (248.747 us; speedup 1.0000x reference)
//
#include <hip/hip_runtime.h>
#include <math.h>

#define CDIM 768
#define NHEADS 12
#define HDIM 64
#define BATCH 4
#define SEQ 2048
#define MTOT (BATCH*SEQ)     // 8192
#define NQKV (3*CDIM)        // 2304
#define QROWS 128            // Q rows per attention block
#define VTILE 4096           // u16 elements per fragmented V tile (16 frag * 64 lane * 4)

typedef __attribute__((ext_vector_type(8))) short bf16x8;
typedef __attribute__((ext_vector_type(4))) short bf16x4;
typedef __attribute__((ext_vector_type(4))) float f32x4;
typedef unsigned short u16;
typedef unsigned int u32;

// async global->LDS, 16B per lane. LDS dest must be wave-uniform base + lane*16
// (global source address is per-lane free-form).
#define ASYNC16(gsrc, ldst) \
  __builtin_amdgcn_global_load_lds((const __attribute__((address_space(1))) void*)(gsrc), \
                                   (__attribute__((address_space(3))) void*)(ldst), 16, 0, 0)

// RNE fp32->bf16 (finite inputs only)
__device__ inline u16 f2b(float x) {
    unsigned int u = __float_as_uint(x);
    return (u16)((u + 0x7fffu + ((u >> 16) & 1u)) >> 16);
}
// rounding-biased uint for pack (p>0 finite): hi16(u+0x8000) = round-half-up bf16
__device__ inline u32 prnd(float x) { return __float_as_uint(x) + 0x8000u; }

// ---------------------------------------------------------------------------
// Fused prologue: x cast (6144 blocks) + 4 weight casts (4*576) + bias concat (9)
// ---------------------------------------------------------------------------
#define XBLK (MTOT*CDIM/1024)        // 6144
#define WBLK (CDIM*CDIM/1024)        // 576
__global__ __launch_bounds__(256)
void prep_kern(const float* __restrict__ x,
               const float* __restrict__ Wq, const float* __restrict__ Wk,
               const float* __restrict__ Wv, const float* __restrict__ Wo,
               const float* __restrict__ bq, const float* __restrict__ bk,
               const float* __restrict__ bv,
               u16* __restrict__ xb, u16* __restrict__ wqkv, u16* __restrict__ wob,
               float* __restrict__ bcat)
{
    int bx = blockIdx.x, tid = threadIdx.x;
    if (bx < XBLK) {
        int i = (bx * 256 + tid) * 4;
        float4 v = *(const float4*)(x + i);
        ushort4 o;
        o.x = f2b(v.x); o.y = f2b(v.y); o.z = f2b(v.z); o.w = f2b(v.w);
        *(ushort4*)(xb + i) = o;
    } else if (bx < XBLK + 4*WBLK) {
        int z = (bx - XBLK) / WBLK;
        int blk = (bx - XBLK) % WBLK;
        const float* src = (z == 0) ? Wq : (z == 1) ? Wk : (z == 2) ? Wv : Wo;
        u16* dst = (z == 3) ? wob : wqkv + (size_t)z * CDIM * CDIM;
        int i = (blk * 256 + tid) * 4;
        float4 v = *(const float4*)(src + i);
        ushort4 o;
        o.x = f2b(v.x); o.y = f2b(v.y); o.z = f2b(v.z); o.w = f2b(v.w);
        *(ushort4*)(dst + i) = o;
    } else {
        int i = (bx - XBLK - 4*WBLK) * 256 + tid;
        if (i < CDIM) bcat[i] = bq[i];
        else if (i < 2*CDIM) bcat[i] = bk[i - CDIM];
        else if (i < 3*CDIM) bcat[i] = bv[i - 2*CDIM];
    }
}

// ---------------------------------------------------------------------------
// bf16 GEMM: Y[m,n] = (sum_k A[m,k]*B[n,k] + bias[n]) * (n<qn ? qscale : 1)
// 128x128 tile, BK=64, 4 waves (2x2 of 64x64), 16x16x32 MFMA, XOR-swizzled
// global_load_lds staging. qscale folds attention 1/sqrt(D) * log2(e) into q.
// ---------------------------------------------------------------------------
template<int OUTF32>
__global__ __launch_bounds__(256)
void gemm_bf16(const u16* __restrict__ A, const u16* __restrict__ B,
               const float* __restrict__ bias, void* __restrict__ Y,
               int N, int K, int qn, float qscale)
{
    __shared__ __align__(16) u16 As[128*64];
    __shared__ __align__(16) u16 Bs[128*64];
    const int tid = threadIdx.x;
    const int m0 = blockIdx.y * 128, n0 = blockIdx.x * 128;
    const int wid = tid >> 6, lane = tid & 63;
    const int wm = (wid & 1) * 64, wn = (wid >> 1) * 64;
    const int l15 = lane & 15, quad = lane >> 4;

    f32x4 acc[4][4];
    #pragma unroll
    for (int i = 0; i < 4; ++i)
        #pragma unroll
        for (int j = 0; j < 4; ++j)
            #pragma unroll
            for (int r = 0; r < 4; ++r) acc[i][j][r] = 0.f;

    for (int k0 = 0; k0 < K; k0 += 64) {
        __syncthreads();
        #pragma unroll
        for (int r = 0; r < 4; ++r) {
            int li = r*256 + tid;
            int row = li >> 3, c = li & 7;
            int gc = c ^ (row & 7);
            ASYNC16(A + (size_t)(m0 + row) * K + k0 + gc*8, &As[li*8]);
            ASYNC16(B + (size_t)(n0 + row) * K + k0 + gc*8, &Bs[li*8]);
        }
        __syncthreads();
        #pragma unroll
        for (int kk = 0; kk < 2; ++kk) {
            bf16x8 a[4], b[4];
            #pragma unroll
            for (int i = 0; i < 4; ++i) {
                int m = wm + i*16 + l15;
                int ca = (kk*4 + quad) ^ (m & 7);
                a[i] = *(const bf16x8*)&As[m*64 + ca*8];
                int n = wn + i*16 + l15;
                int cb = (kk*4 + quad) ^ (n & 7);
                b[i] = *(const bf16x8*)&Bs[n*64 + cb*8];
            }
            #pragma unroll
            for (int i = 0; i < 4; ++i)
                #pragma unroll
                for (int j = 0; j < 4; ++j)
                    acc[i][j] = __builtin_amdgcn_mfma_f32_16x16x32_bf16(a[i], b[j], acc[i][j], 0, 0, 0);
        }
    }

    #pragma unroll
    for (int i = 0; i < 4; ++i) {
        #pragma unroll
        for (int j = 0; j < 4; ++j) {
            int gn = n0 + wn + j*16 + l15;
            float bv = bias[gn];
            float sc = (gn < qn) ? qscale : 1.0f;
            #pragma unroll
            for (int r = 0; r < 4; ++r) {
                int gm = m0 + wm + i*16 + quad*4 + r;
                float v = (acc[i][j][r] + bv) * sc;
                if (OUTF32) ((float*)Y)[(size_t)gm * N + gn] = v;
                else        ((u16*)Y)[(size_t)gm * N + gn] = f2b(v);
            }
        }
    }
}

// ---------------------------------------------------------------------------
// V fragment-ize: qkv V columns -> Vt in EXACT PV-fragment order:
//   Vt[(bh*32 + kt)*VTILE + ((ks*4+jd)*64 + lane)*4 + jj]
//     = V[b, seq = kt*64+ks*16+quad*4+jj, h, d = jd*16+l15]   (lane=quad*16+l15)
// so the attention kernel loads V fragments global->VGPR with zero address math.
// VTILE = 16 frags * 64 lanes * 4 elems = 4096 u16 (8192 BYTES -- round-5 bug
// was using 8192 as the u16 stride).
// ---------------------------------------------------------------------------
__global__ __launch_bounds__(256)
void transpose_v(const u16* __restrict__ QKV, u16* __restrict__ Vt)
{
    __shared__ __align__(16) u16 Vs[64*72];   // [seq within tile][d], stride 72
    const int tid = threadIdx.x;
    const int nt = blockIdx.x, bh = blockIdx.y;
    const int b = bh / NHEADS, h = bh % NHEADS;
    const u16* src = QKV + ((size_t)(b*SEQ + nt*64)) * NQKV + 2*CDIM + h*HDIM;
    #pragma unroll
    for (int rep = 0; rep < 2; ++rep) {
        int li = rep*256 + tid, r = li >> 3, c = li & 7;
        *(uint4*)&Vs[r*72 + c*8] = *(const uint4*)(src + (size_t)r * NQKV + c*8);
    }
    __syncthreads();
    u16* dst = Vt + ((size_t)bh * 32 + nt) * VTILE;
    #pragma unroll
    for (int rep = 0; rep < 2; ++rep) {
        int p = rep*256 + tid;            // 0..511 : (frag, lane-pair)
        int frag = p >> 5;                // 0..15 = ks*4 + jd
        int ks = frag >> 2, jd = frag & 3;
        int lane0 = (p & 31) * 2;
        int quad = lane0 >> 4, l15e = lane0 & 15;
        int d0 = jd*16 + l15e;
        int sb = ks*16 + quad*4;
        u32 r0 = *(const u32*)&Vs[(sb+0)*72 + d0];
        u32 r1 = *(const u32*)&Vs[(sb+1)*72 + d0];
        u32 r2 = *(const u32*)&Vs[(sb+2)*72 + d0];
        u32 r3 = *(const u32*)&Vs[(sb+3)*72 + d0];
        uint4 o;
        o.x = __builtin_amdgcn_perm(r1, r0, 0x05040100u);  // lo16s: lane0 jj0,1
        o.y = __builtin_amdgcn_perm(r3, r2, 0x05040100u);  // lane0 jj2,3
        o.z = __builtin_amdgcn_perm(r1, r0, 0x07060302u);  // hi16s: lane1 jj0,1
        o.w = __builtin_amdgcn_perm(r3, r2, 0x07060302u);  // lane1 jj2,3
        *(uint4*)(dst + (size_t)(frag*64 + lane0) * 4) = o;
    }
}

// ---------------------------------------------------------------------------
// MFMA flash attention. S^T = K.Q^T (C-layout gives lane S[q=l15][k=j*16+
// quad*4+r] == A-operand of 16x16x16 MFMA), exp2 in-register (log2e folded
// into q upstream), P packed via v_perm, PV as K=16 MFMAs. V fragments come
// straight from global (pre-fragmented by transpose_v) in double-buffered
// VGPRs -- no V LDS, no V bank conflicts, no V address math. K double-
// buffered in LDS, 1 barrier/tile. Softmax denom via ones-fragment MFMA.
// ---------------------------------------------------------------------------
__global__ __launch_bounds__(256, 3)
void attn_mfma(const u16* __restrict__ QK, const u16* __restrict__ Vt,
               u16* __restrict__ Oa)
{
    __shared__ __align__(16) u16 Ks[2][64*64];

    const int tid = threadIdx.x;
    const int wid = tid >> 6, lane = tid & 63;
    const int l15 = lane & 15, quad = lane >> 4;
    const int qt = blockIdx.x, bh = blockIdx.y;
    const int b = bh / NHEADS, h = bh % NHEADS;

    const u16* Qg  = QK + ((size_t)(b*SEQ + qt*QROWS)) * NQKV + h*HDIM;
    const u16* Kg0 = QK + ((size_t)(b*SEQ)) * NQKV + CDIM + h*HDIM;
    const uint2* Vg = (const uint2*)(Vt + (size_t)bh * 32 * VTILE);  // [kt][frag*64+lane]

    // ---- prologue: stage K0; V0 frags + Q frags straight to registers ----
    #pragma unroll
    for (int r = 0; r < 2; ++r) {
        int li = r*256 + tid, row = li >> 3, c = li & 7, gc = c ^ (row & 7);
        ASYNC16(Kg0 + (size_t)row * NQKV + gc*8, &Ks[0][li*8]);
    }
    uint2 vb[2][16];
    #pragma unroll
    for (int f = 0; f < 16; ++f) vb[0][f] = Vg[f*64 + lane];

    // Q as B-operand of 16x16x32: B[n=l15][k=quad*8+jj]
    bf16x8 qf[2][2];
    #pragma unroll
    for (int mb = 0; mb < 2; ++mb)
        #pragma unroll
        for (int kk = 0; kk < 2; ++kk)
            qf[mb][kk] = *(const bf16x8*)(Qg + (size_t)(wid*32 + mb*16 + l15) * NQKV + kk*32 + quad*8);

    const bf16x4 ONES = { (short)0x3F80, (short)0x3F80, (short)0x3F80, (short)0x3F80 };

    f32x4 o[2][4];
    #pragma unroll
    for (int mb = 0; mb < 2; ++mb)
        #pragma unroll
        for (int j = 0; j < 4; ++j)
            #pragma unroll
            for (int r = 0; r < 4; ++r) o[mb][j][r] = 0.f;
    f32x4 ll[2];
    #pragma unroll
    for (int mb = 0; mb < 2; ++mb)
        #pragma unroll
        for (int r = 0; r < 4; ++r) ll[mb][r] = 0.f;

    __syncthreads();

    auto body = [&](int kt, int cbuf, int nbuf) {
        if (kt + 1 < SEQ/64) {
            #pragma unroll
            for (int r = 0; r < 2; ++r) {
                int li = r*256 + tid, row = li >> 3, c = li & 7, gc = c ^ (row & 7);
                ASYNC16(Kg0 + (size_t)((kt+1)*64 + row) * NQKV + gc*8, &Ks[nbuf][li*8]);
            }
            const uint2* vsrc = Vg + (size_t)(kt+1) * (VTILE/4);
            #pragma unroll
            for (int f = 0; f < 16; ++f) vb[nbuf][f] = vsrc[f*64 + lane];
        }

        // ---- S^T = K.Q^T : s[mb][j][r] = S[q=mb-block+l15][k=j*16+quad*4+r]
        f32x4 s[2][4];
        #pragma unroll
        for (int mb = 0; mb < 2; ++mb)
            #pragma unroll
            for (int j = 0; j < 4; ++j)
                #pragma unroll
                for (int r = 0; r < 4; ++r) s[mb][j][r] = 0.f;
        #pragma unroll
        for (int kk = 0; kk < 2; ++kk) {
            #pragma unroll
            for (int j = 0; j < 4; ++j) {
                int kr = j*16 + l15;
                int ck = (kk*4 + quad) ^ (kr & 7);
                bf16x8 ak = *(const bf16x8*)&Ks[cbuf][kr*64 + ck*8];
                #pragma unroll
                for (int mb = 0; mb < 2; ++mb)
                    s[mb][j] = __builtin_amdgcn_mfma_f32_16x16x32_bf16(ak, qf[mb][kk], s[mb][j], 0, 0, 0);
            }
        }

        // ---- p = 2^s in-register; pack to 16x16x16 A-fragments ----
        bf16x4 pf[2][4];
        #pragma unroll
        for (int mb = 0; mb < 2; ++mb)
            #pragma unroll
            for (int ks = 0; ks < 4; ++ks) {
                u32 u0 = prnd(__builtin_amdgcn_exp2f(s[mb][ks][0]));
                u32 u1 = prnd(__builtin_amdgcn_exp2f(s[mb][ks][1]));
                u32 u2 = prnd(__builtin_amdgcn_exp2f(s[mb][ks][2]));
                u32 u3 = prnd(__builtin_amdgcn_exp2f(s[mb][ks][3]));
                union { uint2 u; bf16x4 v; } cst;
                cst.u.x = __builtin_amdgcn_perm(u1, u0, 0x07060302u);
                cst.u.y = __builtin_amdgcn_perm(u3, u2, 0x07060302u);
                pf[mb][ks] = cst.v;
            }

        // ---- O += P V ; l += P . 1  (V fragments already in registers) ----
        #pragma unroll
        for (int ks = 0; ks < 4; ++ks) {
            #pragma unroll
            for (int jd = 0; jd < 4; ++jd) {
                union { uint2 u; bf16x4 v; } vv;
                vv.u = vb[cbuf][ks*4 + jd];
                #pragma unroll
                for (int mb = 0; mb < 2; ++mb)
                    o[mb][jd] = __builtin_amdgcn_mfma_f32_16x16x16bf16_1k(pf[mb][ks], vv.v, o[mb][jd], 0, 0, 0);
            }
            #pragma unroll
            for (int mb = 0; mb < 2; ++mb)
                ll[mb] = __builtin_amdgcn_mfma_f32_16x16x16bf16_1k(pf[mb][ks], ONES, ll[mb], 0, 0, 0);
        }
        __syncthreads();   // drains next-tile K asyncs; protects Ks reuse
    };

    for (int kt = 0; kt < SEQ/64; kt += 2) {
        body(kt,   0, 1);
        body(kt+1, 1, 0);
    }

    // ---- epilogue: O rows q = quad*4+r, cols d = jd*16+l15; l same layout ----
    u16* Og = Oa + ((size_t)(b*SEQ + qt*QROWS)) * CDIM + h*HDIM;
    #pragma unroll
    for (int mb = 0; mb < 2; ++mb) {
        #pragma unroll
        for (int r = 0; r < 4; ++r) {
            float inv = 1.f / ll[mb][r];
            int row = wid*32 + mb*16 + quad*4 + r;
            #pragma unroll
            for (int jd = 0; jd < 4; ++jd)
                Og[(size_t)row * CDIM + jd*16 + l15] = f2b(o[mb][jd][r] * inv);
        }
    }
}

// ---------------------------------------------------------------------------
extern "C" void kernel_launch(void* const* d_in, const int* in_sizes, int n_in,
                              void* d_out, int out_size, void* d_ws, size_t ws_size,
                              hipStream_t stream)
{
    const float* x  = (const float*)d_in[0];
    const float* Wq = (const float*)d_in[1];
    const float* bq = (const float*)d_in[2];
    const float* Wk = (const float*)d_in[3];
    const float* bk = (const float*)d_in[4];
    const float* Wv = (const float*)d_in[5];
    const float* bv = (const float*)d_in[6];
    const float* Wo = (const float*)d_in[7];
    const float* bo = (const float*)d_in[8];

    unsigned char* ws = (unsigned char*)d_ws;
    u16* xb   = (u16*)ws;  ws += (size_t)MTOT * CDIM * 2;
    u16* wqkv = (u16*)ws;  ws += (size_t)NQKV * CDIM * 2;
    u16* wob  = (u16*)ws;  ws += (size_t)CDIM * CDIM * 2;
    float* bcat = (float*)ws; ws += (size_t)NQKV * 4;
    u16* qkv  = (u16*)ws;  ws += (size_t)MTOT * NQKV * 2;
    u16* vt   = (u16*)ws;  ws += (size_t)BATCH*NHEADS*32*VTILE * 2;
    u16* ao   = (u16*)ws;

    prep_kern<<<XBLK + 4*WBLK + 9, 256, 0, stream>>>(x, Wq, Wk, Wv, Wo, bq, bk, bv,
                                                     xb, wqkv, wob, bcat);

    // q pre-scaled by log2(e)/sqrt(HDIM) so softmax is a bare exp2
    gemm_bf16<0><<<dim3(NQKV/128, MTOT/128), 256, 0, stream>>>(xb, wqkv, bcat, qkv, NQKV, CDIM, CDIM, 0.18033688f);
    transpose_v<<<dim3(SEQ/64, BATCH*NHEADS), 256, 0, stream>>>(qkv, vt);
    attn_mfma<<<dim3(SEQ/QROWS, BATCH*NHEADS), 256, 0, stream>>>(qkv, vt, ao);
    gemm_bf16<1><<<dim3(CDIM/128, MTOT/128), 256, 0, stream>>>(ao, wob, bo, (float*)d_out, CDIM, CDIM, 0, 1.0f);
}

// Round 7
// 227.754 us; speedup vs baseline: 1.0922x; 1.0922x over previous
//
#include <hip/hip_runtime.h>
#include <math.h>

#define CDIM 768
#define NHEADS 12
#define HDIM 64
#define BATCH 4
#define SEQ 2048
#define MTOT (BATCH*SEQ)     // 8192
#define NQKV (3*CDIM)        // 2304
#define QROWS 128            // Q rows per attention block
#define VTILE 4096           // u16 elements per fragmented V tile (16 frag * 64 lane * 4)

typedef __attribute__((ext_vector_type(8))) short bf16x8;
typedef __attribute__((ext_vector_type(4))) short bf16x4;
typedef __attribute__((ext_vector_type(4))) float f32x4;
typedef unsigned short u16;
typedef unsigned int u32;

// async global->LDS, 16B per lane. LDS dest must be wave-uniform base + lane*16
// (global source address is per-lane free-form).
#define ASYNC16(gsrc, ldst) \
  __builtin_amdgcn_global_load_lds((const __attribute__((address_space(1))) void*)(gsrc), \
                                   (__attribute__((address_space(3))) void*)(ldst), 16, 0, 0)

// RNE fp32->bf16 (finite inputs only)
__device__ inline u16 f2b(float x) {
    unsigned int u = __float_as_uint(x);
    return (u16)((u + 0x7fffu + ((u >> 16) & 1u)) >> 16);
}
// rounding-biased uint for pack: hi16(u+0x8000) = round-half-up-in-magnitude bf16
__device__ inline u32 prnd(float x) { return __float_as_uint(x) + 0x8000u; }

// ---------------------------------------------------------------------------
// Fused prologue: x cast (6144 blocks) + 4 weight casts (4*576) + bias concat (9)
// ---------------------------------------------------------------------------
#define XBLK (MTOT*CDIM/1024)        // 6144
#define WBLK (CDIM*CDIM/1024)        // 576
__global__ __launch_bounds__(256)
void prep_kern(const float* __restrict__ x,
               const float* __restrict__ Wq, const float* __restrict__ Wk,
               const float* __restrict__ Wv, const float* __restrict__ Wo,
               const float* __restrict__ bq, const float* __restrict__ bk,
               const float* __restrict__ bv,
               u16* __restrict__ xb, u16* __restrict__ wqkv, u16* __restrict__ wob,
               float* __restrict__ bcat)
{
    int bx = blockIdx.x, tid = threadIdx.x;
    if (bx < XBLK) {
        int i = (bx * 256 + tid) * 4;
        float4 v = *(const float4*)(x + i);
        ushort4 o;
        o.x = f2b(v.x); o.y = f2b(v.y); o.z = f2b(v.z); o.w = f2b(v.w);
        *(ushort4*)(xb + i) = o;
    } else if (bx < XBLK + 4*WBLK) {
        int z = (bx - XBLK) / WBLK;
        int blk = (bx - XBLK) % WBLK;
        const float* src = (z == 0) ? Wq : (z == 1) ? Wk : (z == 2) ? Wv : Wo;
        u16* dst = (z == 3) ? wob : wqkv + (size_t)z * CDIM * CDIM;
        int i = (blk * 256 + tid) * 4;
        float4 v = *(const float4*)(src + i);
        ushort4 o;
        o.x = f2b(v.x); o.y = f2b(v.y); o.z = f2b(v.z); o.w = f2b(v.w);
        *(ushort4*)(dst + i) = o;
    } else {
        int i = (bx - XBLK - 4*WBLK) * 256 + tid;
        if (i < CDIM) bcat[i] = bq[i];
        else if (i < 2*CDIM) bcat[i] = bk[i - CDIM];
        else if (i < 3*CDIM) bcat[i] = bv[i - 2*CDIM];
    }
}

// ---------------------------------------------------------------------------
// bf16 GEMM: Y[m,n] = (sum_k A[m,k]*B[n,k] + bias[n]) * (n<qn ? qscale : 1)
// 128x128 tile, BK=64, 4 waves (2x2 of 64x64), 16x16x32 MFMA, XOR-swizzled
// global_load_lds staging.
// VFRAG=1: tiles with n0>=1536 (the V columns of the QKV GEMM) are written
// as pre-packed PV fragments into Vt instead of rows into Y. Derivation:
// epilogue element (i,j,r) has seq=gm (jj=r, quad=thread quad), d=gn-1536
// (l15=thread l15, jd=j) -> Vt[(bh*32+kt)*VTILE + ((ks*4+jd)*64 + lane)*4 + r].
// ---------------------------------------------------------------------------
template<int OUTF32, int VFRAG>
__global__ __launch_bounds__(256)
void gemm_bf16(const u16* __restrict__ A, const u16* __restrict__ B,
               const float* __restrict__ bias, void* __restrict__ Y,
               u16* __restrict__ Vt,
               int N, int K, int qn, float qscale)
{
    __shared__ __align__(16) u16 As[128*64];
    __shared__ __align__(16) u16 Bs[128*64];
    const int tid = threadIdx.x;
    const int m0 = blockIdx.y * 128, n0 = blockIdx.x * 128;
    const int wid = tid >> 6, lane = tid & 63;
    const int wm = (wid & 1) * 64, wn = (wid >> 1) * 64;
    const int l15 = lane & 15, quad = lane >> 4;

    f32x4 acc[4][4];
    #pragma unroll
    for (int i = 0; i < 4; ++i)
        #pragma unroll
        for (int j = 0; j < 4; ++j)
            #pragma unroll
            for (int r = 0; r < 4; ++r) acc[i][j][r] = 0.f;

    for (int k0 = 0; k0 < K; k0 += 64) {
        __syncthreads();
        #pragma unroll
        for (int r = 0; r < 4; ++r) {
            int li = r*256 + tid;
            int row = li >> 3, c = li & 7;
            int gc = c ^ (row & 7);
            ASYNC16(A + (size_t)(m0 + row) * K + k0 + gc*8, &As[li*8]);
            ASYNC16(B + (size_t)(n0 + row) * K + k0 + gc*8, &Bs[li*8]);
        }
        __syncthreads();
        #pragma unroll
        for (int kk = 0; kk < 2; ++kk) {
            bf16x8 a[4], b[4];
            #pragma unroll
            for (int i = 0; i < 4; ++i) {
                int m = wm + i*16 + l15;
                int ca = (kk*4 + quad) ^ (m & 7);
                a[i] = *(const bf16x8*)&As[m*64 + ca*8];
                int n = wn + i*16 + l15;
                int cb = (kk*4 + quad) ^ (n & 7);
                b[i] = *(const bf16x8*)&Bs[n*64 + cb*8];
            }
            #pragma unroll
            for (int i = 0; i < 4; ++i)
                #pragma unroll
                for (int j = 0; j < 4; ++j)
                    acc[i][j] = __builtin_amdgcn_mfma_f32_16x16x32_bf16(a[i], b[j], acc[i][j], 0, 0, 0);
        }
    }

    if (VFRAG && n0 >= 2*CDIM) {
        // ---- V tile: write PV fragments straight to Vt ----
        #pragma unroll
        for (int i = 0; i < 4; ++i) {
            int gm = m0 + wm + i*16 + quad*4;      // seq base for r=0..3
            int bb = gm >> 11;                     // batch
            int kt = (gm & 2047) >> 6;
            int ks = (gm & 63) >> 4;
            #pragma unroll
            for (int j = 0; j < 4; ++j) {
                int gn = n0 + wn + j*16 + l15;
                float bv = bias[gn];
                int d = gn - 2*CDIM;
                int h = d >> 6, jd = (d & 63) >> 4;  // jd == j
                int bh = bb * NHEADS + h;
                u32 p0 = prnd(acc[i][j][0] + bv);
                u32 p1 = prnd(acc[i][j][1] + bv);
                u32 p2 = prnd(acc[i][j][2] + bv);
                u32 p3 = prnd(acc[i][j][3] + bv);
                uint2 st;
                st.x = __builtin_amdgcn_perm(p1, p0, 0x07060302u);
                st.y = __builtin_amdgcn_perm(p3, p2, 0x07060302u);
                *(uint2*)(Vt + ((size_t)(bh*32 + kt))*VTILE + (size_t)((ks*4 + jd)*64 + lane)*4) = st;
            }
        }
    } else {
        #pragma unroll
        for (int i = 0; i < 4; ++i) {
            #pragma unroll
            for (int j = 0; j < 4; ++j) {
                int gn = n0 + wn + j*16 + l15;
                float bv = bias[gn];
                float sc = (gn < qn) ? qscale : 1.0f;
                #pragma unroll
                for (int r = 0; r < 4; ++r) {
                    int gm = m0 + wm + i*16 + quad*4 + r;
                    float v = (acc[i][j][r] + bv) * sc;
                    if (OUTF32) ((float*)Y)[(size_t)gm * N + gn] = v;
                    else        ((u16*)Y)[(size_t)gm * N + gn] = f2b(v);
                }
            }
        }
    }
}

// ---------------------------------------------------------------------------
// MFMA flash attention. S^T = K.Q^T (C-layout gives lane S[q=l15][k=j*16+
// quad*4+r] == A-operand of 16x16x16 MFMA), exp2 in-register (log2e folded
// into q upstream), P packed via v_perm, PV as K=16 MFMAs. V tiles staged
// into LDS in FRAGMENT order (pre-fragmented by the QKV GEMM epilogue):
// fragment read = ds_read_b64 at (frag*64+lane)*4 u16 -> stride 8 B/lane ->
// 2-way bank aliasing = free, LDS shared across waves (round-6 VGPR
// privatization quadrupled V traffic; this keeps both fixes).
// K + V double-buffered in LDS, 1 barrier/tile. l via ones-fragment MFMA.
// ---------------------------------------------------------------------------
__global__ __launch_bounds__(256, 3)
void attn_mfma(const u16* __restrict__ QK, const u16* __restrict__ Vt,
               u16* __restrict__ Oa)
{
    __shared__ __align__(16) u16 Ks[2][64*64];
    __shared__ __align__(16) u16 Vls[2][VTILE];

    const int tid = threadIdx.x;
    const int wid = tid >> 6, lane = tid & 63;
    const int l15 = lane & 15, quad = lane >> 4;
    const int qt = blockIdx.x, bh = blockIdx.y;
    const int b = bh / NHEADS, h = bh % NHEADS;

    const u16* Qg  = QK + ((size_t)(b*SEQ + qt*QROWS)) * NQKV + h*HDIM;
    const u16* Kg0 = QK + ((size_t)(b*SEQ)) * NQKV + CDIM + h*HDIM;
    const u16* Vg  = Vt + (size_t)bh * 32 * VTILE;   // + kt*VTILE per tile

    // ---- prologue: stage K0/V0; Q frags straight to registers ----
    #pragma unroll
    for (int r = 0; r < 2; ++r) {
        int li = r*256 + tid, row = li >> 3, c = li & 7, gc = c ^ (row & 7);
        ASYNC16(Kg0 + (size_t)row * NQKV + gc*8, &Ks[0][li*8]);
        ASYNC16(Vg + li*8, &Vls[0][li*8]);
    }

    // Q as B-operand of 16x16x32: B[n=l15][k=quad*8+jj]
    bf16x8 qf[2][2];
    #pragma unroll
    for (int mb = 0; mb < 2; ++mb)
        #pragma unroll
        for (int kk = 0; kk < 2; ++kk)
            qf[mb][kk] = *(const bf16x8*)(Qg + (size_t)(wid*32 + mb*16 + l15) * NQKV + kk*32 + quad*8);

    const bf16x4 ONES = { (short)0x3F80, (short)0x3F80, (short)0x3F80, (short)0x3F80 };

    f32x4 o[2][4];
    #pragma unroll
    for (int mb = 0; mb < 2; ++mb)
        #pragma unroll
        for (int j = 0; j < 4; ++j)
            #pragma unroll
            for (int r = 0; r < 4; ++r) o[mb][j][r] = 0.f;
    f32x4 ll[2];
    #pragma unroll
    for (int mb = 0; mb < 2; ++mb)
        #pragma unroll
        for (int r = 0; r < 4; ++r) ll[mb][r] = 0.f;

    __syncthreads();

    auto body = [&](int kt, int cbuf, int nbuf) {
        if (kt + 1 < SEQ/64) {
            #pragma unroll
            for (int r = 0; r < 2; ++r) {
                int li = r*256 + tid, row = li >> 3, c = li & 7, gc = c ^ (row & 7);
                ASYNC16(Kg0 + (size_t)((kt+1)*64 + row) * NQKV + gc*8, &Ks[nbuf][li*8]);
                ASYNC16(Vg + (size_t)(kt+1) * VTILE + li*8, &Vls[nbuf][li*8]);
            }
        }

        // ---- S^T = K.Q^T : s[mb][j][r] = S[q=mb-block+l15][k=j*16+quad*4+r]
        f32x4 s[2][4];
        #pragma unroll
        for (int mb = 0; mb < 2; ++mb)
            #pragma unroll
            for (int j = 0; j < 4; ++j)
                #pragma unroll
                for (int r = 0; r < 4; ++r) s[mb][j][r] = 0.f;
        #pragma unroll
        for (int kk = 0; kk < 2; ++kk) {
            #pragma unroll
            for (int j = 0; j < 4; ++j) {
                int kr = j*16 + l15;
                int ck = (kk*4 + quad) ^ (kr & 7);
                bf16x8 ak = *(const bf16x8*)&Ks[cbuf][kr*64 + ck*8];
                #pragma unroll
                for (int mb = 0; mb < 2; ++mb)
                    s[mb][j] = __builtin_amdgcn_mfma_f32_16x16x32_bf16(ak, qf[mb][kk], s[mb][j], 0, 0, 0);
            }
        }

        // ---- p = 2^s in-register; pack to 16x16x16 A-fragments ----
        bf16x4 pf[2][4];
        #pragma unroll
        for (int mb = 0; mb < 2; ++mb)
            #pragma unroll
            for (int ks = 0; ks < 4; ++ks) {
                u32 u0 = prnd(__builtin_amdgcn_exp2f(s[mb][ks][0]));
                u32 u1 = prnd(__builtin_amdgcn_exp2f(s[mb][ks][1]));
                u32 u2 = prnd(__builtin_amdgcn_exp2f(s[mb][ks][2]));
                u32 u3 = prnd(__builtin_amdgcn_exp2f(s[mb][ks][3]));
                union { uint2 u; bf16x4 v; } cst;
                cst.u.x = __builtin_amdgcn_perm(u1, u0, 0x07060302u);
                cst.u.y = __builtin_amdgcn_perm(u3, u2, 0x07060302u);
                pf[mb][ks] = cst.v;
            }

        // ---- O += P V ; l += P . 1  (V fragments: conflict-free ds_read_b64)
        #pragma unroll
        for (int ks = 0; ks < 4; ++ks) {
            #pragma unroll
            for (int jd = 0; jd < 4; ++jd) {
                bf16x4 vv = *(const bf16x4*)&Vls[cbuf][(size_t)((ks*4 + jd)*64 + lane)*4];
                #pragma unroll
                for (int mb = 0; mb < 2; ++mb)
                    o[mb][jd] = __builtin_amdgcn_mfma_f32_16x16x16bf16_1k(pf[mb][ks], vv, o[mb][jd], 0, 0, 0);
            }
            #pragma unroll
            for (int mb = 0; mb < 2; ++mb)
                ll[mb] = __builtin_amdgcn_mfma_f32_16x16x16bf16_1k(pf[mb][ks], ONES, ll[mb], 0, 0, 0);
        }
        __syncthreads();   // drains next-tile asyncs; protects buffer reuse
    };

    for (int kt = 0; kt < SEQ/64; kt += 2) {
        body(kt,   0, 1);
        body(kt+1, 1, 0);
    }

    // ---- epilogue: O rows q = quad*4+r, cols d = jd*16+l15; l same layout ----
    u16* Og = Oa + ((size_t)(b*SEQ + qt*QROWS)) * CDIM + h*HDIM;
    #pragma unroll
    for (int mb = 0; mb < 2; ++mb) {
        #pragma unroll
        for (int r = 0; r < 4; ++r) {
            float inv = 1.f / ll[mb][r];
            int row = wid*32 + mb*16 + quad*4 + r;
            #pragma unroll
            for (int jd = 0; jd < 4; ++jd)
                Og[(size_t)row * CDIM + jd*16 + l15] = f2b(o[mb][jd][r] * inv);
        }
    }
}

// ---------------------------------------------------------------------------
extern "C" void kernel_launch(void* const* d_in, const int* in_sizes, int n_in,
                              void* d_out, int out_size, void* d_ws, size_t ws_size,
                              hipStream_t stream)
{
    const float* x  = (const float*)d_in[0];
    const float* Wq = (const float*)d_in[1];
    const float* bq = (const float*)d_in[2];
    const float* Wk = (const float*)d_in[3];
    const float* bk = (const float*)d_in[4];
    const float* Wv = (const float*)d_in[5];
    const float* bv = (const float*)d_in[6];
    const float* Wo = (const float*)d_in[7];
    const float* bo = (const float*)d_in[8];

    unsigned char* ws = (unsigned char*)d_ws;
    u16* xb   = (u16*)ws;  ws += (size_t)MTOT * CDIM * 2;
    u16* wqkv = (u16*)ws;  ws += (size_t)NQKV * CDIM * 2;
    u16* wob  = (u16*)ws;  ws += (size_t)CDIM * CDIM * 2;
    float* bcat = (float*)ws; ws += (size_t)NQKV * 4;
    u16* qkv  = (u16*)ws;  ws += (size_t)MTOT * NQKV * 2;
    u16* vt   = (u16*)ws;  ws += (size_t)BATCH*NHEADS*32*VTILE * 2;
    u16* ao   = (u16*)ws;

    prep_kern<<<XBLK + 4*WBLK + 9, 256, 0, stream>>>(x, Wq, Wk, Wv, Wo, bq, bk, bv,
                                                     xb, wqkv, wob, bcat);

    // q pre-scaled by log2(e)/sqrt(HDIM) so softmax is a bare exp2
    gemm_bf16<0,1><<<dim3(NQKV/128, MTOT/128), 256, 0, stream>>>(xb, wqkv, bcat, qkv, vt, NQKV, CDIM, CDIM, 0.18033688f);
    attn_mfma<<<dim3(SEQ/QROWS, BATCH*NHEADS), 256, 0, stream>>>(qkv, vt, ao);
    gemm_bf16<1,0><<<dim3(CDIM/128, MTOT/128), 256, 0, stream>>>(ao, wob, bo, (float*)d_out, nullptr, CDIM, CDIM, 0, 1.0f);
}